// Round 6
// baseline (2757.294 us; speedup 1.0000x reference)
//
#include <hip/hip_runtime.h>
#include <math.h>

#define HH 128
#define NPIX 16384
#define BB 8
#define MM 4096
#define NN 16384
#define LRELU_S 0.1f
#define NBLK 256

typedef __attribute__((ext_vector_type(8))) short bf16x8;
typedef __attribute__((ext_vector_type(4))) float f32x4;

__device__ __forceinline__ float leaky_(float v){ return v >= 0.f ? v : LRELU_S*v; }
__device__ __forceinline__ float clamp01(float v){ return fminf(fmaxf(v, 0.f), 1.f); }
__device__ __forceinline__ float clamp02(float v){ return fminf(fmaxf(v, 0.f), 2.f); }
__device__ __forceinline__ unsigned short f2bf(float f){
  unsigned u = __float_as_uint(f);
  u = (u + 0x7FFFu + ((u >> 16) & 1u)) >> 16;
  return (unsigned short)u;
}
__device__ __forceinline__ float bf2f(unsigned short s){
  return __uint_as_float(((unsigned)s) << 16);
}

// ---------- prep: A f32 -> Abf[m][n] bf16 ----------
__global__ __launch_bounds__(256) void k_prep(const float* __restrict__ A_,
                                              unsigned short* __restrict__ Abf){
  size_t i = ((size_t)blockIdx.x*256 + threadIdx.x)*8;
  float4 v0 = *(const float4*)&A_[i];
  float4 v1 = *(const float4*)&A_[i+4];
  unsigned short o[8] = { f2bf(v0.x), f2bf(v0.y), f2bf(v0.z), f2bf(v0.w),
                          f2bf(v1.x), f2bf(v1.y), f2bf(v1.z), f2bf(v1.w) };
  *(uint4*)&Abf[i] = *(uint4*)o;
}

// ---------- dn[b] = ||d[b,:]|| ----------
__global__ __launch_bounds__(256) void k_dn(const float* __restrict__ d, float* __restrict__ dn){
  int b = blockIdx.x, t = threadIdx.x;
  float ss = 0.f;
  for (int m=t; m<MM; m+=256){ float v = d[b*MM + m]; ss += v*v; }
  #pragma unroll
  for (int off=32; off; off>>=1) ss += __shfl_down(ss, off);
  __shared__ float red[4];
  if ((t & 63) == 0) red[t>>6] = ss;
  __syncthreads();
  if (t == 0) dn[b] = sqrtf(red[0]+red[1]+red[2]+red[3]);
}

// ---------- grid barrier (all NBLK blocks co-resident) ----------
__device__ __forceinline__ void gbar(int* cnt, unsigned* gen){
  __syncthreads();
  if (threadIdx.x == 0){
    __threadfence();
    unsigned g = __hip_atomic_load(gen, __ATOMIC_RELAXED, __HIP_MEMORY_SCOPE_AGENT);
    int a = __hip_atomic_fetch_add(cnt, 1, __ATOMIC_ACQ_REL, __HIP_MEMORY_SCOPE_AGENT);
    if (a == NBLK-1){
      __hip_atomic_store(cnt, 0, __ATOMIC_RELAXED, __HIP_MEMORY_SCOPE_AGENT);
      __hip_atomic_store(gen, g+1u, __ATOMIC_RELEASE, __HIP_MEMORY_SCOPE_AGENT);
    } else {
      while (__hip_atomic_load(gen, __ATOMIC_ACQUIRE, __HIP_MEMORY_SCOPE_AGENT) == g)
        __builtin_amdgcn_s_sleep(4);
    }
    __threadfence();
  }
  __syncthreads();
}

// ---------- megakernel: 9 iterations, 3 phases each ----------
__global__ __launch_bounds__(256) void k_mega(
    const unsigned short* __restrict__ Abf, const float* __restrict__ d_,
    const float* __restrict__ wK, const float* __restrict__ w1, const float* __restrict__ b1,
    const float* __restrict__ w2, const float* __restrict__ b2,
    const float* __restrict__ w3, const float* __restrict__ b3,
    const float* __restrict__ delta, const float* __restrict__ alpha,
    const float* __restrict__ beta, const float* __restrict__ dn,
    float* __restrict__ x, unsigned short* __restrict__ xtt,
    float* __restrict__ rk1, float* __restrict__ e_, float* __restrict__ d2p,
    float* __restrict__ up, int* bar_cnt, unsigned* bar_gen){
  __shared__ float smem[10752];           // union: conv bufs / gemm1 part / gemm2 zs
  __shared__ float wKs[18], w1s[100], w2s[100], w3s[100], bs[6], cf_s[8], red8s[64];
  __shared__ float scal[2];               // twoa, beta
  int blk = blockIdx.x, t = threadIdx.x;
  // conv aliases
  float (*xs)[128]   = (float(*)[128])&smem[0];        // 20 rows
  float (*bufA)[18][128] = (float(*)[18][128])&smem[2560];
  float (*bufB)[14][128] = (float(*)[14][128])&smem[7168];
  // gemm1 aliases
  float (*part)[16][16] = (float(*)[16][16])&smem[0];  // 4*16*16
  float (*p2)[16] = (float(*)[16])&smem[1024];
  // gemm2 alias
  float (*zs)[256] = (float(*)[256])&smem[0];          // 8*256

  for (int i=t;i<18;i+=256) wKs[i]=wK[i];
  for (int i=t;i<100;i+=256){ w1s[i]=w1[i]; w2s[i]=w2[i]; w3s[i]=w3[i]; }
  if (t<2){ bs[t]=b1[t]; bs[2+t]=b2[t]; bs[4+t]=b3[t]; }
  if (t==0){ scal[0] = 2.f*clamp02(alpha[0]); scal[1] = clamp02(beta[0]); }
  __syncthreads();

  for (int it=0; it<9; ++it){
    // ============ Phase A: conv chain (slab=4 rows) + gemm1 ============
    {
      int b = blk >> 5, slab = blk & 31, r0 = slab*4;
      for (int idx=t; idx<20*128; idx+=256){
        int i = idx>>7, j = idx&127, ir = r0-8+i;
        xs[i][j] = ((unsigned)ir < 128u) ? x[b*NPIX + ir*HH + j] : 0.f;
      }
      __syncthreads();
      for (int c=0;c<2;++c)                       // Kx: 18 rows, ir=r0-7+i
        for (int idx=t; idx<18*128; idx+=256){
          int i = idx>>7, j = idx&127, ir = r0-7+i;
          float s = 0.f;
          if ((unsigned)ir < 128u){
            #pragma unroll
            for (int di=0;di<3;++di)
              #pragma unroll
              for (int dj=0;dj<3;++dj){
                int jj = j+dj-1;
                if ((unsigned)jj < 128u) s += xs[i+di][jj]*wKs[(c*3+di)*3+dj];
              }
          }
          bufA[c][i][j] = s;
        }
      __syncthreads();
      for (int o=0;o<2;++o)                       // s1: 14 rows, ir=r0-5+i
        for (int idx=t; idx<14*128; idx+=256){
          int i = idx>>7, j = idx&127, ir = r0-5+i;
          float v = 0.f;
          if ((unsigned)ir < 128u){
            float s = bs[o];
            #pragma unroll
            for (int c=0;c<2;++c)
              #pragma unroll
              for (int di=0;di<5;++di)
                #pragma unroll
                for (int dj=0;dj<5;++dj){
                  int jj = j+dj-2;
                  if ((unsigned)jj < 128u) s += bufA[c][i+di][jj]*w1s[(o*2+c)*25+di*5+dj];
                }
            v = bufA[o][i+2][j] + leaky_(s);
          }
          bufB[o][i][j] = v;
        }
      __syncthreads();
      for (int o=0;o<2;++o)                       // s2: 10 rows, ir=r0-3+i
        for (int idx=t; idx<10*128; idx+=256){
          int i = idx>>7, j = idx&127, ir = r0-3+i;
          float v = 0.f;
          if ((unsigned)ir < 128u){
            float s = bs[2+o];
            #pragma unroll
            for (int c=0;c<2;++c)
              #pragma unroll
              for (int di=0;di<5;++di)
                #pragma unroll
                for (int dj=0;dj<5;++dj){
                  int jj = j+dj-2;
                  if ((unsigned)jj < 128u) s += bufB[c][i+di][jj]*w2s[(o*2+c)*25+di*5+dj];
                }
            v = bufB[o][i+2][j] + leaky_(s);
          }
          bufA[o][i][j] = v;
        }
      __syncthreads();
      for (int o=0;o<2;++o)                       // s3: 6 rows, ir=r0-1+i
        for (int idx=t; idx<6*128; idx+=256){
          int i = idx>>7, j = idx&127, ir = r0-1+i;
          float v = 0.f;
          if ((unsigned)ir < 128u){
            float s = bs[4+o];
            #pragma unroll
            for (int c=0;c<2;++c)
              #pragma unroll
              for (int di=0;di<5;++di)
                #pragma unroll
                for (int dj=0;dj<5;++dj){
                  int jj = j+dj-2;
                  if ((unsigned)jj < 128u) s += bufA[c][i+di][jj]*w3s[(o*2+c)*25+di*5+dj];
                }
            v = bufA[o][i+2][j] + leaky_(s);
          }
          bufB[o][i][j] = v;
        }
      __syncthreads();
      for (int c=0;c<2;++c)                       // nu: 6 rows, ir=r0-1+i
        for (int idx=t; idx<6*128; idx+=256){
          int i = idx>>7, j = idx&127, ir = r0-1+i;
          float v = 0.f;
          if ((unsigned)ir < 128u){
            float kx = 0.f;
            #pragma unroll
            for (int di=0;di<3;++di)
              #pragma unroll
              for (int dj=0;dj<3;++dj){
                int jj = j+dj-1;
                if ((unsigned)jj < 128u) kx += xs[i+6+di][jj]*wKs[(c*3+di)*3+dj];
              }
            v = scal[0]*(kx - bufB[c][i][j]);
          }
          bufA[c][i][j] = v;
        }
      __syncthreads();
      for (int idx=t; idx<4*128; idx+=256){       // convKt: 4 rows, ir=r0+i
        int i = idx>>7, j = idx&127, ir = r0+i;
        float s = 0.f;
        #pragma unroll
        for (int c=0;c<2;++c)
          #pragma unroll
          for (int di=0;di<3;++di)
            #pragma unroll
            for (int dj=0;dj<3;++dj){
              int jj = j+dj-1;
              if ((unsigned)jj < 128u) s += bufA[c][i+di][jj]*wKs[(c*3+(2-di))*3+(2-dj)];
            }
        rk1[b*NPIX + ir*HH + j] = s;
      }
      __syncthreads();
    }
    // ---- gemm1 (4-wave k-split; mt = blk) ----
    {
      int mt = blk;
      int w = t >> 6, lane = t & 63;
      int kg = lane >> 4, col = lane & 15;
      const unsigned short* Ap = Abf + (size_t)(mt*16 + col)*NN + w*4096 + kg*8;
      const unsigned short* Bp = xtt + ((size_t)(w*512 + kg)*16 + col)*8;
      f32x4 acc = {0.f,0.f,0.f,0.f};
      #pragma unroll 8
      for (int s=0; s<128; ++s){
        bf16x8 a = *(const bf16x8*)(Ap + s*32);
        bf16x8 b = *(const bf16x8*)(Bp + s*512);
        acc = __builtin_amdgcn_mfma_f32_16x16x32_bf16(a, b, acc, 0, 0, 0);
      }
      #pragma unroll
      for (int j=0;j<4;++j) part[w][kg*4+j][col] = acc[j];
      __syncthreads();
      {
        int r = t >> 4, b = t & 15;
        float s = part[0][r][b] + part[1][r][b] + part[2][r][b] + part[3][r][b];
        int m = mt*16 + r;
        float ee = s - ((b < 8) ? d_[b*MM + m] : 0.f);
        e_[m*16 + b] = ee;
        p2[r][b] = (b < 8) ? ee*ee : 0.f;
      }
      __syncthreads();
      if (t < 8){
        float s2 = 0.f;
        #pragma unroll
        for (int r2=0;r2<16;++r2) s2 += p2[r2][t];
        d2p[mt*8 + t] = s2;
      }
    }
    gbar(bar_cnt, bar_gen);
    // ============ Phase B: gemm2 partials (ms=blk>>4, nb=blk&15) ============
    {
      if (t < 64){
        int b = t & 7, prt = t >> 3;
        float s = 0.f;
        for (int i=0;i<32;++i) s += d2p[(prt*32+i)*8 + b];
        red8s[prt*8 + b] = s;
      }
      __syncthreads();
      if (t < 8){
        float s2 = 0.f;
        #pragma unroll
        for (int p=0;p<8;++p) s2 += red8s[p*8 + t];
        float dist = fmaxf(sqrtf(s2), 1e-10f);
        float de = expf(delta[0]);
        cf_s[t] = scal[0]*(1.f - fminf(1.f, de*dn[t]/dist));
      }
      __syncthreads();
      int ms = blk >> 4, nb = blk & 15;
      int m0 = ms*256, n0 = nb*1024;
      for (int i=t; i<8*256; i+=256){
        int ml = i >> 3, b = i & 7;
        zs[b][ml] = cf_s[b]*e_[(size_t)(m0+ml)*16 + b];
      }
      __syncthreads();
      float4 acc[BB];
      #pragma unroll
      for (int b=0;b<BB;++b){ acc[b].x=0.f; acc[b].y=0.f; acc[b].z=0.f; acc[b].w=0.f; }
      const unsigned short* Ap = Abf + (size_t)m0*NN + n0 + t*4;
      #pragma unroll 4
      for (int ml=0; ml<256; ++ml){
        uint2 araw = *(const uint2*)(Ap + (size_t)ml*NN);
        float a0 = bf2f((unsigned short)(araw.x & 0xffff));
        float a1 = bf2f((unsigned short)(araw.x >> 16));
        float a2 = bf2f((unsigned short)(araw.y & 0xffff));
        float a3 = bf2f((unsigned short)(araw.y >> 16));
        #pragma unroll
        for (int b=0;b<BB;++b){
          float s = zs[b][ml];
          acc[b].x += a0*s; acc[b].y += a1*s; acc[b].z += a2*s; acc[b].w += a3*s;
        }
      }
      #pragma unroll
      for (int b=0;b<BB;++b)
        *(float4*)&up[((size_t)ms*BB + b)*NN + n0 + t*4] = acc[b];
      __syncthreads();
    }
    gbar(bar_cnt, bar_gen);
    // ============ Phase C: combine + xtt pack ============
    {
      float bta = scal[1];
      #pragma unroll
      for (int h=0; h<2; ++h){
        int o = h*65536 + blk*256 + t;         // 131072 outputs
        int b = o >> 14, pix = o & 16383;
        float s = rk1[b*NPIX + pix];
        #pragma unroll
        for (int ms=0; ms<16; ++ms)
          s += up[((size_t)ms*BB + b)*NN + pix];
        float xn = clamp01(x[b*NPIX + pix] - bta*s);
        x[b*NPIX + pix] = xn;
        xtt[((size_t)(pix>>3)*16 + b)*8 + (pix&7)] = f2bf(xn);
      }
    }
    if (it < 8) gbar(bar_cnt, bar_gen);
  }
}

extern "C" void kernel_launch(void* const* d_in, const int* in_sizes, int n_in,
                              void* d_out, int out_size, void* d_ws, size_t ws_size,
                              hipStream_t stream) {
  const float* d_d   = (const float*)d_in[0];
  const float* d_A   = (const float*)d_in[1];
  const float* w1    = (const float*)d_in[2];
  const float* b1    = (const float*)d_in[3];
  const float* w2    = (const float*)d_in[4];
  const float* b2    = (const float*)d_in[5];
  const float* w3    = (const float*)d_in[6];
  const float* b3    = (const float*)d_in[7];
  const float* wK    = (const float*)d_in[8];
  const float* delta = (const float*)d_in[9];
  const float* alpha = (const float*)d_in[10];
  const float* beta  = (const float*)d_in[12];

  char* p = (char*)d_ws;
  unsigned short* Abf = (unsigned short*)p; p += (size_t)MM*NN*2;      // 128 MiB
  unsigned short* xtt = (unsigned short*)p; p += (size_t)2048*16*8*2;  // 512 KiB
  float* x   = (float*)p; p += (size_t)BB*NPIX*4;
  float* rk1 = (float*)p; p += (size_t)BB*NPIX*4;
  float* e_  = (float*)p; p += (size_t)MM*16*4;                        // 256 KiB
  float* up  = (float*)p; p += (size_t)16*BB*NN*4;                     // 8 MiB
  float* d2p = (float*)p; p += (size_t)256*8*4;
  float* dnb = (float*)p; p += 64;
  int* bar   = (int*)p;  p += 64;

  k_prep<<<MM*NN/(256*8), 256, 0, stream>>>(d_A, Abf);
  k_dn<<<BB, 256, 0, stream>>>(d_d, dnb);
  hipMemsetAsync(x, 0, (size_t)BB*NPIX*4, stream);
  hipMemsetAsync(xtt, 0, (size_t)2048*16*8*2, stream);
  hipMemsetAsync(bar, 0, 8, stream);

  k_mega<<<NBLK, 256, 0, stream>>>(Abf, d_d, wK, w1, b1, w2, b2, w3, b3,
                                   delta, alpha, beta, dnb,
                                   x, xtt, rk1, e_, d2p, up,
                                   bar, (unsigned*)(bar+1));

  hipMemcpyAsync(d_out, x, (size_t)BB*NPIX*4, hipMemcpyDeviceToDevice, stream);
}